// Round 3
// baseline (107684.912 us; speedup 1.0000x reference)
//
#include <hip/hip_runtime.h>
#include <hip/hip_bf16.h>
#include <math.h>

// Problem constants: V=32000, D=256, H=256, L=2, C=2, B=64, T=1024, PAD=0
namespace {
constexpr int Bn = 64;
constexpr int Tn = 1024;
constexpr int Dn = 256;
constexpr int Hn = 256;
}

typedef __attribute__((ext_vector_type(8))) short short8;
typedef __attribute__((ext_vector_type(4))) float f32x4;

template <typename T>
__device__ __forceinline__ float ldf(const T* p, long i);
template <>
__device__ __forceinline__ float ldf<float>(const float* p, long i) { return p[i]; }
template <>
__device__ __forceinline__ float ldf<__hip_bfloat16>(const __hip_bfloat16* p, long i) {
  return __bfloat162float(p[i]);
}

__device__ __forceinline__ float sigmf(float x) { return 1.0f / (1.0f + __expf(-x)); }
__device__ __forceinline__ float tanh_fast(float x) { return 1.0f - 2.0f / (__expf(2.0f * x) + 1.0f); }

// ---------------------------------------------------------------------------
// Dtype detector (validated round 2: flag=1 -> f32 inputs).
// ---------------------------------------------------------------------------
__global__ void k_detect(const unsigned short* __restrict__ e, int* __restrict__ flag) {
  __shared__ int sbuf[256];
  int bad = 0;
  for (int i = threadIdx.x; i < 4096; i += 256) {
    const unsigned short v = e[i];
    const int ex = (v >> 7) & 0xFF;
    bad += (ex >= 137) ? 1 : 0;
  }
  sbuf[threadIdx.x] = bad;
  __syncthreads();
  for (int s = 128; s > 0; s >>= 1) {
    if (threadIdx.x < s) sbuf[threadIdx.x] += sbuf[threadIdx.x + s];
    __syncthreads();
  }
  if (threadIdx.x == 0) flag[0] = (sbuf[0] > 64) ? 1 : 0;
}

__global__ void k_lengths(const int* __restrict__ x, int* __restrict__ len) {
  const int b = blockIdx.x;
  int cnt = 0;
  for (int t = threadIdx.x; t < Tn; t += blockDim.x) cnt += (x[b * Tn + t] != 0) ? 1 : 0;
  __shared__ int sbuf[256];
  sbuf[threadIdx.x] = cnt;
  __syncthreads();
  for (int s = 128; s > 0; s >>= 1) {
    if (threadIdx.x < s) sbuf[threadIdx.x] += sbuf[threadIdx.x + s];
    __syncthreads();
  }
  if (threadIdx.x == 0) len[b] = sbuf[0];
}

// ===========================================================================
// FAST PATH
// ===========================================================================

// biases -> f32 [4][1024] (order: f0,b0,f1,b1); zero sync counters.
__global__ void k_prep_small(const void* b0f, const void* b0b, const void* b1f, const void* b1b,
                             const int* __restrict__ flag, float* __restrict__ biasbuf,
                             unsigned* __restrict__ ctr) {
  const int tid = threadIdx.x;
  if (tid < 8) ctr[tid] = 0;
  const bool isf32 = flag[0] != 0;
  for (int idx = tid; idx < 4096; idx += 256) {
    const int j = idx >> 10, col = idx & 1023;
    const void* src = (j == 0) ? b0f : (j == 1) ? b0b : (j == 2) ? b1f : b1b;
    biasbuf[idx] = isf32 ? ((const float*)src)[col]
                         : __bfloat162float(((const __hip_bfloat16*)src)[col]);
  }
}

// Transpose+convert W[(H+XK) x 1024] -> WhT bf16 [1024][256], WxT bf16 [1024][XK].
// grid (12, 16, 4): z = which W (f0,b0,f1,b1); x = 64-row k-tile; y = 64-col n-tile.
__global__ void k_prepw(const void* W0, const void* W1, const void* W2, const void* W3,
                        const int* __restrict__ flag, __hip_bfloat16* __restrict__ whT,
                        __hip_bfloat16* __restrict__ wxT0, __hip_bfloat16* __restrict__ wxT1) {
  const int j = blockIdx.z;
  const int rows = (j < 2) ? 512 : 768;
  const int bx = blockIdx.x;
  if (bx * 64 >= rows) return;
  const int by = blockIdx.y;
  const void* W = (j == 0) ? W0 : (j == 1) ? W1 : (j == 2) ? W2 : W3;
  const bool isf32 = flag[0] != 0;
  __shared__ float tile[64][65];
  const int tid = threadIdx.x;
  const int c = tid & 63, r4 = tid >> 6;
#pragma unroll
  for (int rep = 0; rep < 16; ++rep) {
    const int rr = r4 * 16 + rep;
    const size_t idx = (size_t)(bx * 64 + rr) * 1024 + by * 64 + c;
    tile[rr][c] = isf32 ? ((const float*)W)[idx]
                        : __bfloat162float(((const __hip_bfloat16*)W)[idx]);
  }
  __syncthreads();
  const int kk = tid & 63;
#pragma unroll
  for (int rep = 0; rep < 16; ++rep) {
    const int a = r4 * 16 + rep;
    const int n = by * 64 + a;
    const int k = bx * 64 + kk;
    const __hip_bfloat16 v = __float2bfloat16(tile[kk][a]);
    if (k < 256) {
      whT[(size_t)j * (1024 * 256) + (size_t)n * 256 + k] = v;
    } else {
      const int k2 = k - 256;
      if (j < 2)
        wxT0[(size_t)j * (1024 * 256) + (size_t)n * 256 + k2] = v;
      else
        wxT1[(size_t)(j - 2) * (1024 * 512) + (size_t)n * 512 + k2] = v;
    }
  }
}

// Embedding gather -> xemb[t][b][256] bf16. grid (1024), 256 thr.
__global__ void k_gather(const int* __restrict__ x, const void* __restrict__ E,
                         const int* __restrict__ flag, __hip_bfloat16* __restrict__ xemb) {
  const int t = blockIdx.x, tid = threadIdx.x;
  const bool isf32 = flag[0] != 0;
  for (int b = 0; b < 64; ++b) {
    const int tok = x[b * Tn + t];
    const float v = isf32 ? ((const float*)E)[(size_t)tok * Dn + tid]
                          : __bfloat162float(((const __hip_bfloat16*)E)[(size_t)tok * Dn + tid]);
    xemb[((size_t)t * 64 + b) * 256 + tid] = __float2bfloat16(v);
  }
}

// ---------------------------------------------------------------------------
// xproj GEMM: out[d][m][1024] f32 = A[m][K] bf16 @ WT_d^T + bias_d.
// WT stored [1024 cols][K] (K-contiguous). grid (M/64, 16, 2); 256 thr, 4 waves.
// MFMA 16x16x32 bf16. A-frag: row=lane&15, k=(lane>>4)*8+j. B mirror. D: row=quad*4+r, col=lane&15.
// ---------------------------------------------------------------------------
__launch_bounds__(256, 2)
__global__ void k_xproj(const __hip_bfloat16* __restrict__ A, const int K,
                        const __hip_bfloat16* __restrict__ WT0,
                        const __hip_bfloat16* __restrict__ WT1, const float* __restrict__ bias0,
                        const float* __restrict__ bias1, float* __restrict__ out) {
  const int bx = blockIdx.x, by = blockIdx.y, dz = blockIdx.z;
  const __hip_bfloat16* __restrict__ WT = dz ? WT1 : WT0;
  const float* __restrict__ bias = dz ? bias1 : bias0;
  float* __restrict__ o = out + (size_t)dz * (1024ull * 64 * 1024);
  const int tid = threadIdx.x, w = tid >> 6, L = tid & 63, quad = L >> 4, l16 = L & 15;
  const int mrow = bx * 64 + w * 16;
  f32x4 acc[4];
#pragma unroll
  for (int nt = 0; nt < 4; ++nt) {
    const float bv = bias[by * 64 + nt * 16 + l16];
    acc[nt][0] = bv; acc[nt][1] = bv; acc[nt][2] = bv; acc[nt][3] = bv;
  }
  const int nk = K >> 5;
  for (int kc = 0; kc < nk; ++kc) {
    const short8 a = *(const short8*)(A + (size_t)(mrow + l16) * K + kc * 32 + quad * 8);
#pragma unroll
    for (int nt = 0; nt < 4; ++nt) {
      const short8 b =
          *(const short8*)(WT + (size_t)(by * 64 + nt * 16 + l16) * K + kc * 32 + quad * 8);
      acc[nt] = __builtin_amdgcn_mfma_f32_16x16x32_bf16(a, b, acc[nt], 0, 0, 0);
    }
  }
#pragma unroll
  for (int nt = 0; nt < 4; ++nt)
#pragma unroll
    for (int r = 0; r < 4; ++r)
      o[(size_t)(mrow + quad * 4 + r) * 1024 + by * 64 + nt * 16 + l16] = acc[nt][r];
}

// ---------------------------------------------------------------------------
// Recurrent layer. 8 blocks: blockIdx.x = d*4+q. Block (d,q) owns units
// u in [q*64, q*64+64); wave w owns units w*16..+15 as its 4 gate N-tiles, so
// lane L holds z_f,z_i,z_g,z_o of unit u = q*64+w*16+(L&15) for 16 batches.
// Wh chunk register-resident (32 x short8 = 128 VGPRs). h exchanged through a
// double-buffered global mailbox + per-dir monotonic atomic counter barrier.
// ---------------------------------------------------------------------------
template <bool WRITE_SEQ>
__launch_bounds__(256, 1) __global__
void k_lstm_fast(const __hip_bfloat16* __restrict__ WhT,  // [2][1024][256] (this layer)
                 const float* __restrict__ xproj,          // [2][T][64][1024] f32
                 const int* __restrict__ lengths, unsigned* __restrict__ ctr,  // [2]
                 __hip_bfloat16* __restrict__ hglob,       // [2][2][64][256]
                 __hip_bfloat16* __restrict__ seq0,        // [T][64][512]
                 float* __restrict__ hfin) {               // [2][64][256]
  const int d = blockIdx.x >> 2;
  const int q = blockIdx.x & 3;
  const int tid = threadIdx.x;
  const int w = tid >> 6, L = tid & 63, quad = L >> 4, l16 = L & 15;
  const int u = q * 64 + w * 16 + l16;

  __shared__ __hip_bfloat16 h_lds[64][264];  // row stride 264 -> 2-way LDS alias max (free)

  for (int idx = tid; idx < 64 * 264; idx += 256) (&h_lds[0][0])[idx] = __float2bfloat16(0.0f);

  // Register-resident Wh chunk: wfrag[gate][kchunk]
  const __hip_bfloat16* __restrict__ Wd = WhT + (size_t)d * (1024 * 256);
  short8 wfrag[4][8];
#pragma unroll
  for (int g = 0; g < 4; ++g)
#pragma unroll
    for (int kc = 0; kc < 8; ++kc)
      wfrag[g][kc] =
          *(const short8*)(Wd + (size_t)(g * 256 + u) * 256 + kc * 32 + quad * 8);

  float c_reg[16], h_reg[16];
  int len_b[16];
#pragma unroll
  for (int mt = 0; mt < 4; ++mt)
#pragma unroll
    for (int r = 0; r < 4; ++r) {
      c_reg[mt * 4 + r] = 0.0f;
      h_reg[mt * 4 + r] = 0.0f;
      len_b[mt * 4 + r] = lengths[mt * 16 + quad * 4 + r];
    }
  const float* __restrict__ xp = xproj + (size_t)d * (1024ull * 64 * 1024);
  unsigned* myctr = ctr + d;
  __hip_bfloat16* __restrict__ hg = hglob + (size_t)d * (2 * 64 * 256);
  __syncthreads();

  for (int s = 0; s < Tn; ++s) {
    const int t = d ? (Tn - 1 - s) : s;

    // 1. C-init from xproj (independent of the barrier -> latency hidden by spin)
    f32x4 acc[4][4];
#pragma unroll
    for (int mt = 0; mt < 4; ++mt) {
      const float* __restrict__ xrow =
          xp + ((size_t)t * 64 + mt * 16 + quad * 4) * 1024 + q * 64 + w * 16 + l16;
#pragma unroll
      for (int g = 0; g < 4; ++g)
#pragma unroll
        for (int r = 0; r < 4; ++r) acc[mt][g][r] = xrow[(size_t)r * 1024 + g * 256];
    }

    // 2. finish previous step's h exchange
    if (s > 0) {
      if (tid == 0) {
        while (__hip_atomic_load(myctr, __ATOMIC_RELAXED, __HIP_MEMORY_SCOPE_AGENT) <
               4u * (unsigned)s)
          __builtin_amdgcn_s_sleep(1);
      }
      __syncthreads();
      __threadfence();  // acquire: invalidate L1 before reading peers' h
      const __hip_bfloat16* __restrict__ src = hg + ((s - 1) & 1) * (64 * 256);
#pragma unroll
      for (int i = 0; i < 8; ++i) {
        const int flat = i * 256 + tid;
        const int b = flat >> 5, c8 = (flat & 31) * 8;
        *(short8*)&h_lds[b][c8] = *(const short8*)(src + b * 256 + c8);
      }
      __syncthreads();
    }

    // 3. z += h @ Wh
#pragma unroll
    for (int kc = 0; kc < 8; ++kc) {
#pragma unroll
      for (int mt = 0; mt < 4; ++mt) {
        const short8 a = *(const short8*)&h_lds[mt * 16 + l16][kc * 32 + quad * 8];
#pragma unroll
        for (int g = 0; g < 4; ++g)
          acc[mt][g] = __builtin_amdgcn_mfma_f32_16x16x32_bf16(a, wfrag[g][kc], acc[mt][g], 0, 0, 0);
      }
    }

    // 4. gates + state update (lane-local: all 4 gates of unit u in this lane)
    __hip_bfloat16* __restrict__ dst = hg + (s & 1) * (64 * 256);
#pragma unroll
    for (int mt = 0; mt < 4; ++mt)
#pragma unroll
      for (int r = 0; r < 4; ++r) {
        const int idx = mt * 4 + r, b = mt * 16 + quad * 4 + r;
        const float fg = sigmf(acc[mt][0][r]);
        const float ig = sigmf(acc[mt][1][r]);
        const float gg = tanh_fast(acc[mt][2][r]);
        const float og = sigmf(acc[mt][3][r]);
        const float cn = fg * c_reg[idx] + ig * gg;
        const float hn = og * tanh_fast(cn);
        if (t < len_b[idx]) {
          c_reg[idx] = cn;
          h_reg[idx] = hn;
        }
        dst[b * 256 + u] = __float2bfloat16(h_reg[idx]);
        if (WRITE_SEQ)
          seq0[((size_t)t * 64 + b) * 512 + d * 256 + u] = __float2bfloat16(h_reg[idx]);
      }

    // 5. publish
    __threadfence();  // release: drain stores to L2 (coherence point)
    __syncthreads();
    if (tid == 0) __hip_atomic_fetch_add(myctr, 1u, __ATOMIC_RELEASE, __HIP_MEMORY_SCOPE_AGENT);
  }

  if (!WRITE_SEQ) {
#pragma unroll
    for (int mt = 0; mt < 4; ++mt)
#pragma unroll
      for (int r = 0; r < 4; ++r) {
        const int b = mt * 16 + quad * 4 + r;
        hfin[((size_t)d * 64 + b) * 256 + u] = h_reg[mt * 4 + r];
      }
  }
}

// ===========================================================================
// SLOW FALLBACK PATH (round-2 passing version, used when ws is too small)
// ===========================================================================
template <typename TW, int XK, bool WRITE_SEQ>
__device__ __forceinline__ void lstm_body(const int* __restrict__ x, const TW* __restrict__ E,
                                          const __hip_bfloat16* __restrict__ seq_in,
                                          const TW* __restrict__ W, const TW* __restrict__ bias,
                                          const int len, const int b, const int dir,
                                          __hip_bfloat16* __restrict__ seq_out,
                                          float* __restrict__ hfin) {
  const int j = threadIdx.x;
  __shared__ float h[Hn];
  __shared__ float xb[XK];
  float hj = 0.0f, cj = 0.0f;
  h[j] = 0.0f;
  const float bfj = ldf(bias, j);
  const float bij = ldf(bias, Hn + j);
  const float bgj = ldf(bias, 2 * Hn + j);
  const float boj = ldf(bias, 3 * Hn + j);
  __syncthreads();
  for (int s = 0; s < Tn; ++s) {
    const int t = dir ? (Tn - 1 - s) : s;
    const bool active = (t < len);
    if (active) {
      if constexpr (XK == Dn) {
        const int tok = x[b * Tn + t];
        xb[j] = ldf(E, (long)tok * Dn + j);
      } else {
        const long base = ((long)(b * Tn + t)) * (2 * Hn);
        xb[j] = __bfloat162float(seq_in[base + j]);
        xb[j + Hn] = __bfloat162float(seq_in[base + j + Hn]);
      }
      __syncthreads();
      float af = bfj, ai = bij, ag = bgj, ao = boj;
#pragma unroll 4
      for (int k = 0; k < Hn; ++k) {
        const float hk = h[k];
        const long r = (long)k * (4 * Hn);
        af += hk * ldf(W, r + j);
        ai += hk * ldf(W, r + Hn + j);
        ag += hk * ldf(W, r + 2 * Hn + j);
        ao += hk * ldf(W, r + 3 * Hn + j);
      }
#pragma unroll 4
      for (int k = 0; k < XK; ++k) {
        const float xk = xb[k];
        const long r = (long)(Hn + k) * (4 * Hn);
        af += xk * ldf(W, r + j);
        ai += xk * ldf(W, r + Hn + j);
        ag += xk * ldf(W, r + 2 * Hn + j);
        ao += xk * ldf(W, r + 3 * Hn + j);
      }
      const float fg = 1.0f / (1.0f + expf(-af));
      const float ig = 1.0f / (1.0f + expf(-ai));
      const float gg = tanhf(ag);
      const float og = 1.0f / (1.0f + expf(-ao));
      const float cn = fg * cj + ig * gg;
      const float hn = og * tanhf(cn);
      __syncthreads();
      hj = hn;
      cj = cn;
      h[j] = hn;
      __syncthreads();
    }
    if constexpr (WRITE_SEQ) {
      seq_out[((long)(b * Tn + t)) * (2 * Hn) + dir * Hn + j] = __float2bfloat16(hj);
    }
  }
  if constexpr (!WRITE_SEQ) hfin[(dir * Bn + b) * Hn + j] = hj;
}

template <int XK, bool WRITE_SEQ>
__global__ void k_lstm(const int* __restrict__ x, const void* __restrict__ E,
                       const __hip_bfloat16* __restrict__ seq_in, const void* __restrict__ Wf,
                       const void* __restrict__ bf, const void* __restrict__ Wb,
                       const void* __restrict__ bb, const int* __restrict__ lengths,
                       const int* __restrict__ flag, __hip_bfloat16* __restrict__ seq_out,
                       float* __restrict__ hfin) {
  const int b = blockIdx.x & (Bn - 1);
  const int dir = blockIdx.x >> 6;
  const int len = lengths[b];
  const void* W = dir ? Wb : Wf;
  const void* bias = dir ? bb : bf;
  if (flag[0]) {
    lstm_body<float, XK, WRITE_SEQ>(x, (const float*)E, seq_in, (const float*)W,
                                    (const float*)bias, len, b, dir, seq_out, hfin);
  } else {
    lstm_body<__hip_bfloat16, XK, WRITE_SEQ>(x, (const __hip_bfloat16*)E, seq_in,
                                             (const __hip_bfloat16*)W, (const __hip_bfloat16*)bias,
                                             len, b, dir, seq_out, hfin);
  }
}

// ---------------------------------------------------------------------------
template <typename TW>
__device__ __forceinline__ void fc_body(const float* __restrict__ hfin, const TW* __restrict__ Wfc,
                                        const TW* __restrict__ bfc, TW* __restrict__ out) {
  const int idx = threadIdx.x;
  const int b = idx >> 1;
  const int cc = idx & 1;
  float acc = ldf(bfc, cc);
  for (int k = 0; k < Hn; ++k) acc += hfin[(0 * Bn + b) * Hn + k] * ldf(Wfc, k * 2 + cc);
  for (int k = 0; k < Hn; ++k) acc += hfin[(1 * Bn + b) * Hn + k] * ldf(Wfc, (Hn + k) * 2 + cc);
  if constexpr (sizeof(TW) == 2) {
    out[b * 2 + cc] = __float2bfloat16(acc);
  } else {
    out[b * 2 + cc] = acc;
  }
}

__global__ void k_fc(const float* __restrict__ hfin, const void* __restrict__ Wfc,
                     const void* __restrict__ bfc, const int* __restrict__ flag,
                     void* __restrict__ out) {
  if (flag[0]) {
    fc_body<float>(hfin, (const float*)Wfc, (const float*)bfc, (float*)out);
  } else {
    fc_body<__hip_bfloat16>(hfin, (const __hip_bfloat16*)Wfc, (const __hip_bfloat16*)bfc,
                            (__hip_bfloat16*)out);
  }
}

// ---------------------------------------------------------------------------
extern "C" void kernel_launch(void* const* d_in, const int* in_sizes, int n_in,
                              void* d_out, int out_size, void* d_ws, size_t ws_size,
                              hipStream_t stream) {
  const int* x = (const int*)d_in[0];
  const void* E = d_in[1];
  const void* Wf0 = d_in[2];
  const void* bf0 = d_in[3];
  const void* Wb0 = d_in[4];
  const void* bb0 = d_in[5];
  const void* Wf1 = d_in[6];
  const void* bf1 = d_in[7];
  const void* Wb1 = d_in[8];
  const void* bb1 = d_in[9];
  const void* Wfc = d_in[10];
  const void* bfc = d_in[11];

  char* ws = (char*)d_ws;
  int* flag = (int*)ws;                // @0
  unsigned* ctr = (unsigned*)(ws + 64);  // 8 u32
  int* lengths = (int*)(ws + 256);

  const size_t MB = 1ull << 20;
  const size_t FAST_NEED = 615 * MB;

  k_detect<<<1, 256, 0, stream>>>((const unsigned short*)E, flag);
  k_lengths<<<Bn, 256, 0, stream>>>(x, lengths);

  if (ws_size >= FAST_NEED) {
    float* biasbuf = (float*)(ws + 4096);                    // 4*1024 f32
    __hip_bfloat16* whT = (__hip_bfloat16*)(ws + 1 * MB);    // [4][1024][256]
    __hip_bfloat16* wxT0 = (__hip_bfloat16*)(ws + 3 * MB);   // [2][1024][256]
    __hip_bfloat16* wxT1 = (__hip_bfloat16*)(ws + 4 * MB);   // [2][1024][512]
    __hip_bfloat16* hglob = (__hip_bfloat16*)(ws + 6 * MB);  // [2][2][64][256]
    float* hfin = (float*)(ws + 6 * MB + 256 * 1024);        // [2][64][256] f32
    __hip_bfloat16* xemb = (__hip_bfloat16*)(ws + 7 * MB);   // [1024][64][256]
    __hip_bfloat16* seq0 = (__hip_bfloat16*)(ws + 39 * MB);  // [1024][64][512]
    float* xproj = (float*)(ws + 103 * MB);                  // [2][1024][64][1024] f32

    k_prep_small<<<1, 256, 0, stream>>>(bf0, bb0, bf1, bb1, flag, biasbuf, ctr);
    k_prepw<<<dim3(12, 16, 4), 256, 0, stream>>>(Wf0, Wb0, Wf1, Wb1, flag, whT, wxT0, wxT1);
    k_gather<<<Tn, 256, 0, stream>>>(x, E, flag, xemb);

    // layer 0
    k_xproj<<<dim3(1024, 16, 2), 256, 0, stream>>>(xemb, 256, wxT0, wxT0 + 1024 * 256, biasbuf,
                                                   biasbuf + 1024, xproj);
    k_lstm_fast<true><<<8, 256, 0, stream>>>(whT, xproj, lengths, ctr, hglob, seq0, nullptr);
    // layer 1
    k_xproj<<<dim3(1024, 16, 2), 256, 0, stream>>>(seq0, 512, wxT1, wxT1 + 1024 * 512,
                                                   biasbuf + 2048, biasbuf + 3072, xproj);
    k_lstm_fast<false><<<8, 256, 0, stream>>>(whT + 2 * 1024 * 256, xproj, lengths, ctr + 2, hglob,
                                              nullptr, hfin);
    k_fc<<<1, 128, 0, stream>>>(hfin, Wfc, bfc, flag, d_out);
  } else {
    // slow fallback (round-2 passing path)
    __hip_bfloat16* seq0 = (__hip_bfloat16*)(ws + 4096);
    const size_t seq0_bytes = (size_t)Bn * Tn * 2 * Hn * sizeof(__hip_bfloat16);
    float* hfin = (float*)(ws + 4096 + seq0_bytes);
    k_lstm<Dn, true><<<2 * Bn, 256, 0, stream>>>(x, E, nullptr, Wf0, bf0, Wb0, bb0, lengths, flag,
                                                 seq0, nullptr);
    k_lstm<2 * Hn, false><<<2 * Bn, 256, 0, stream>>>(x, E, seq0, Wf1, bf1, Wb1, bb1, lengths,
                                                      flag, nullptr, hfin);
    k_fc<<<1, 128, 0, stream>>>(hfin, Wfc, bfc, flag, d_out);
  }
}

// Round 4
// 20595.000 us; speedup vs baseline: 5.2287x; 5.2287x over previous
//
#include <hip/hip_runtime.h>
#include <hip/hip_bf16.h>
#include <math.h>

// Problem constants: V=32000, D=256, H=256, L=2, C=2, B=64, T=1024, PAD=0
namespace {
constexpr int Bn = 64;
constexpr int Tn = 1024;
constexpr int Dn = 256;
constexpr int Hn = 256;
}

typedef __attribute__((ext_vector_type(8))) short short8;
typedef __attribute__((ext_vector_type(4))) float f32x4;

template <typename T>
__device__ __forceinline__ float ldf(const T* p, long i);
template <>
__device__ __forceinline__ float ldf<float>(const float* p, long i) { return p[i]; }
template <>
__device__ __forceinline__ float ldf<__hip_bfloat16>(const __hip_bfloat16* p, long i) {
  return __bfloat162float(p[i]);
}

__device__ __forceinline__ float sigmf(float x) { return 1.0f / (1.0f + __expf(-x)); }
__device__ __forceinline__ float tanh_fast(float x) {
  return 1.0f - 2.0f / (__expf(2.0f * x) + 1.0f);
}

// ---------------------------------------------------------------------------
// Dtype detector (validated round 2: flag=1 -> f32 inputs).
// ---------------------------------------------------------------------------
__global__ void k_detect(const unsigned short* __restrict__ e, int* __restrict__ flag) {
  __shared__ int sbuf[256];
  int bad = 0;
  for (int i = threadIdx.x; i < 4096; i += 256) {
    const unsigned short v = e[i];
    const int ex = (v >> 7) & 0xFF;
    bad += (ex >= 137) ? 1 : 0;
  }
  sbuf[threadIdx.x] = bad;
  __syncthreads();
  for (int s = 128; s > 0; s >>= 1) {
    if (threadIdx.x < s) sbuf[threadIdx.x] += sbuf[threadIdx.x + s];
    __syncthreads();
  }
  if (threadIdx.x == 0) flag[0] = (sbuf[0] > 64) ? 1 : 0;
}

__global__ void k_lengths(const int* __restrict__ x, int* __restrict__ len) {
  const int b = blockIdx.x;
  int cnt = 0;
  for (int t = threadIdx.x; t < Tn; t += blockDim.x) cnt += (x[b * Tn + t] != 0) ? 1 : 0;
  __shared__ int sbuf[256];
  sbuf[threadIdx.x] = cnt;
  __syncthreads();
  for (int s = 128; s > 0; s >>= 1) {
    if (threadIdx.x < s) sbuf[threadIdx.x] += sbuf[threadIdx.x + s];
    __syncthreads();
  }
  if (threadIdx.x == 0) len[b] = sbuf[0];
}

// ===========================================================================
// FAST PATH
// ===========================================================================

// biases -> f32 [4][1024] (order: f0,b0,f1,b1); zero sync counters.
__global__ void k_prep_small(const void* b0f, const void* b0b, const void* b1f, const void* b1b,
                             const int* __restrict__ flag, float* __restrict__ biasbuf,
                             unsigned* __restrict__ ctr) {
  const int tid = threadIdx.x;
  if (tid < 8) ctr[tid] = 0;
  const bool isf32 = flag[0] != 0;
  for (int idx = tid; idx < 4096; idx += 256) {
    const int j = idx >> 10, col = idx & 1023;
    const void* src = (j == 0) ? b0f : (j == 1) ? b0b : (j == 2) ? b1f : b1b;
    biasbuf[idx] = isf32 ? ((const float*)src)[col]
                         : __bfloat162float(((const __hip_bfloat16*)src)[col]);
  }
}

// Transpose+convert W[(H+XK) x 1024] -> WhT bf16 [1024][256], WxT bf16 [1024][XK].
// grid (12, 16, 4): z = which W (f0,b0,f1,b1); x = 64-row k-tile; y = 64-col n-tile.
__global__ void k_prepw(const void* W0, const void* W1, const void* W2, const void* W3,
                        const int* __restrict__ flag, __hip_bfloat16* __restrict__ whT,
                        __hip_bfloat16* __restrict__ wxT0, __hip_bfloat16* __restrict__ wxT1) {
  const int j = blockIdx.z;
  const int rows = (j < 2) ? 512 : 768;
  const int bx = blockIdx.x;
  if (bx * 64 >= rows) return;
  const int by = blockIdx.y;
  const void* W = (j == 0) ? W0 : (j == 1) ? W1 : (j == 2) ? W2 : W3;
  const bool isf32 = flag[0] != 0;
  __shared__ float tile[64][65];
  const int tid = threadIdx.x;
  const int c = tid & 63, r4 = tid >> 6;
#pragma unroll
  for (int rep = 0; rep < 16; ++rep) {
    const int rr = r4 * 16 + rep;
    const size_t idx = (size_t)(bx * 64 + rr) * 1024 + by * 64 + c;
    tile[rr][c] = isf32 ? ((const float*)W)[idx]
                        : __bfloat162float(((const __hip_bfloat16*)W)[idx]);
  }
  __syncthreads();
  const int kk = tid & 63;
#pragma unroll
  for (int rep = 0; rep < 16; ++rep) {
    const int a = r4 * 16 + rep;
    const int n = by * 64 + a;
    const int k = bx * 64 + kk;
    const __hip_bfloat16 v = __float2bfloat16(tile[kk][a]);
    if (k < 256) {
      whT[(size_t)j * (1024 * 256) + (size_t)n * 256 + k] = v;
    } else {
      const int k2 = k - 256;
      if (j < 2)
        wxT0[(size_t)j * (1024 * 256) + (size_t)n * 256 + k2] = v;
      else
        wxT1[(size_t)(j - 2) * (1024 * 512) + (size_t)n * 512 + k2] = v;
    }
  }
}

// ---------------------------------------------------------------------------
// Phased xproj GEMM. One block = one timestep (64 batch rows) x 64 gate cols.
// grid (Tc, 16, 2). LAYER 0: A rows gathered from E (token lookup, K=256).
// LAYER 1: A rows from seq0 (K=512). Output local slot tl = blockIdx.x:
// xp[dz][tl][b][1024] f32, t_global = (dz ? t0b : t0f) + tl.
// ---------------------------------------------------------------------------
template <int LAYER>
__launch_bounds__(256, 2)
__global__ void k_xproj(const int* __restrict__ x, const void* __restrict__ E,
                        const int* __restrict__ flag, const __hip_bfloat16* __restrict__ seq0,
                        const __hip_bfloat16* __restrict__ WT,  // [2][1024][K]
                        const float* __restrict__ bias,         // [2][1024]
                        float* __restrict__ xp,                 // [2][Tc][64][1024]
                        const int t0f, const int t0b, const int Tc) {
  constexpr int K = (LAYER == 0) ? 256 : 512;
  constexpr int NK = K / 32;
  const int tl = blockIdx.x, by = blockIdx.y, dz = blockIdx.z;
  const int t = (dz ? t0b : t0f) + tl;
  const int tid = threadIdx.x, w = tid >> 6, L = tid & 63, quad = L >> 4, l16 = L & 15;
  const __hip_bfloat16* __restrict__ WTd = WT + (size_t)dz * (1024 * K);
  const float* __restrict__ bsd = bias + dz * 1024;
  float* __restrict__ o = xp + (size_t)(dz * Tc + tl) * (64 * 1024);

  // A-fragment: row b = w*16 + l16 (wave w owns m-tile w), k = kc*32 + quad*8 + j
  short8 afrag[NK];
  const int bA = w * 16 + l16;
  if constexpr (LAYER == 0) {
    const int tok = x[bA * Tn + t];
    if (flag[0]) {
      const float* __restrict__ er = (const float*)E + (size_t)tok * Dn;
#pragma unroll
      for (int kc = 0; kc < NK; ++kc) {
        short8 a;
#pragma unroll
        for (int jj = 0; jj < 8; ++jj) {
          const __hip_bfloat16 hv = __float2bfloat16(er[kc * 32 + quad * 8 + jj]);
          a[jj] = *(const short*)&hv;
        }
        afrag[kc] = a;
      }
    } else {
      const __hip_bfloat16* __restrict__ er = (const __hip_bfloat16*)E + (size_t)tok * Dn;
#pragma unroll
      for (int kc = 0; kc < NK; ++kc) afrag[kc] = *(const short8*)(er + kc * 32 + quad * 8);
    }
  } else {
    const __hip_bfloat16* __restrict__ ar = seq0 + ((size_t)t * 64 + bA) * 512;
#pragma unroll
    for (int kc = 0; kc < NK; ++kc) afrag[kc] = *(const short8*)(ar + kc * 32 + quad * 8);
  }

  f32x4 acc[4];
#pragma unroll
  for (int nt = 0; nt < 4; ++nt) {
    const float bv = bsd[by * 64 + nt * 16 + l16];
    acc[nt][0] = bv; acc[nt][1] = bv; acc[nt][2] = bv; acc[nt][3] = bv;
  }
#pragma unroll
  for (int kc = 0; kc < NK; ++kc) {
#pragma unroll
    for (int nt = 0; nt < 4; ++nt) {
      const short8 b =
          *(const short8*)(WTd + (size_t)(by * 64 + nt * 16 + l16) * K + kc * 32 + quad * 8);
      acc[nt] = __builtin_amdgcn_mfma_f32_16x16x32_bf16(afrag[kc], b, acc[nt], 0, 0, 0);
    }
  }
#pragma unroll
  for (int nt = 0; nt < 4; ++nt)
#pragma unroll
    for (int r = 0; r < 4; ++r)
      o[(size_t)(w * 16 + quad * 4 + r) * 1024 + by * 64 + nt * 16 + l16] = acc[nt][r];
}

// ---------------------------------------------------------------------------
// Phased recurrent layer. 8 blocks: blockIdx.x = d*4+q. Block (d,q) owns units
// [q*64, q*64+64); wave w owns units w*16..+15; lane L holds z_f,i,g,o of unit
// u = q*64+w*16+(L&15) for 16 batches. Wh register-resident (128 VGPR/lane).
// h exchanged via double-buffered global mailbox + per-dir monotone counter;
// counters/mailbox parity continue across phase launches (wait uses absolute s).
// h/c state carried across phases in cstate/hstate (f32).
// ---------------------------------------------------------------------------
template <bool WRITE_SEQ>
__launch_bounds__(256, 1) __global__
void k_lstm_fast(const __hip_bfloat16* __restrict__ WhT,  // [2][1024][256] this layer
                 const float* __restrict__ xproj,          // [2][Tc][64][1024] f32
                 const int* __restrict__ lengths, unsigned* __restrict__ ctr,  // [2]
                 __hip_bfloat16* __restrict__ hglob,       // [2][2][64][256]
                 float* __restrict__ cstate, float* __restrict__ hstate,  // [2][64][256]
                 __hip_bfloat16* __restrict__ seq0,        // [T][64][512]
                 const int s0, const int Tc) {
  const int d = blockIdx.x >> 2;
  const int q = blockIdx.x & 3;
  const int tid = threadIdx.x;
  const int w = tid >> 6, L = tid & 63, quad = L >> 4, l16 = L & 15;
  const int u = q * 64 + w * 16 + l16;

  __shared__ __hip_bfloat16 h_lds[64][264];
  for (int idx = tid; idx < 64 * 264; idx += 256) (&h_lds[0][0])[idx] = __float2bfloat16(0.0f);

  const __hip_bfloat16* __restrict__ Wd = WhT + (size_t)d * (1024 * 256);
  short8 wfrag[4][8];
#pragma unroll
  for (int g = 0; g < 4; ++g)
#pragma unroll
    for (int kc = 0; kc < 8; ++kc)
      wfrag[g][kc] = *(const short8*)(Wd + (size_t)(g * 256 + u) * 256 + kc * 32 + quad * 8);

  float c_reg[16], h_reg[16];
  int len_b[16];
#pragma unroll
  for (int mt = 0; mt < 4; ++mt)
#pragma unroll
    for (int r = 0; r < 4; ++r) {
      const int idx = mt * 4 + r;
      const int b = mt * 16 + quad * 4 + r;
      len_b[idx] = lengths[b];
      if (s0 == 0) {
        c_reg[idx] = 0.0f;
        h_reg[idx] = 0.0f;
      } else {
        c_reg[idx] = cstate[((size_t)(d * 64 + b) << 8) + u];
        h_reg[idx] = hstate[((size_t)(d * 64 + b) << 8) + u];
      }
    }
  unsigned* myctr = ctr + d;
  __hip_bfloat16* __restrict__ hg = hglob + (size_t)d * (2 * 64 * 256);
  __syncthreads();

  for (int sl = 0; sl < Tc; ++sl) {
    const int s = s0 + sl;
    const int t = d ? (Tn - 1 - s) : s;
    const int tl = d ? (Tc - 1 - sl) : sl;

    // 1. C-init from xproj (issued before the spin -> latency hidden)
    f32x4 acc[4][4];
#pragma unroll
    for (int mt = 0; mt < 4; ++mt) {
      const float* __restrict__ xrow =
          xproj + ((size_t)(d * Tc + tl) * 64 + mt * 16 + quad * 4) * 1024 + u;
#pragma unroll
      for (int g = 0; g < 4; ++g)
#pragma unroll
        for (int r = 0; r < 4; ++r) acc[mt][g][r] = xrow[(size_t)r * 1024 + g * 256];
    }

    // 2. finish previous step's h exchange
    if (s > 0) {
      if (tid == 0) {
        while (__hip_atomic_load(myctr, __ATOMIC_RELAXED, __HIP_MEMORY_SCOPE_AGENT) <
               4u * (unsigned)s)
          __builtin_amdgcn_s_sleep(1);
      }
      __syncthreads();
      __threadfence();  // acquire
      const __hip_bfloat16* __restrict__ src = hg + ((s - 1) & 1) * (64 * 256);
#pragma unroll
      for (int i = 0; i < 8; ++i) {
        const int flat = i * 256 + tid;
        const int b = flat >> 5, c8 = (flat & 31) * 8;
        *(short8*)&h_lds[b][c8] = *(const short8*)(src + b * 256 + c8);
      }
      __syncthreads();
    }

    // 3. z += h @ Wh
#pragma unroll
    for (int kc = 0; kc < 8; ++kc) {
#pragma unroll
      for (int mt = 0; mt < 4; ++mt) {
        const short8 a = *(const short8*)&h_lds[mt * 16 + l16][kc * 32 + quad * 8];
#pragma unroll
        for (int g = 0; g < 4; ++g)
          acc[mt][g] =
              __builtin_amdgcn_mfma_f32_16x16x32_bf16(a, wfrag[g][kc], acc[mt][g], 0, 0, 0);
      }
    }

    // 4. gates + state update (lane-local)
    __hip_bfloat16* __restrict__ dst = hg + (s & 1) * (64 * 256);
#pragma unroll
    for (int mt = 0; mt < 4; ++mt)
#pragma unroll
      for (int r = 0; r < 4; ++r) {
        const int idx = mt * 4 + r, b = mt * 16 + quad * 4 + r;
        const float fg = sigmf(acc[mt][0][r]);
        const float ig = sigmf(acc[mt][1][r]);
        const float gg = tanh_fast(acc[mt][2][r]);
        const float og = sigmf(acc[mt][3][r]);
        const float cn = fg * c_reg[idx] + ig * gg;
        const float hn = og * tanh_fast(cn);
        if (t < len_b[idx]) {
          c_reg[idx] = cn;
          h_reg[idx] = hn;
        }
        dst[b * 256 + u] = __float2bfloat16(h_reg[idx]);
        if (WRITE_SEQ)
          seq0[((size_t)t * 64 + b) * 512 + d * 256 + u] = __float2bfloat16(h_reg[idx]);
      }

    // 5. publish
    __threadfence();  // release
    __syncthreads();
    if (tid == 0) __hip_atomic_fetch_add(myctr, 1u, __ATOMIC_RELEASE, __HIP_MEMORY_SCOPE_AGENT);
  }

  // save h/c for the next phase (hstate doubles as hfin for the last layer)
#pragma unroll
  for (int mt = 0; mt < 4; ++mt)
#pragma unroll
    for (int r = 0; r < 4; ++r) {
      const int idx = mt * 4 + r, b = mt * 16 + quad * 4 + r;
      cstate[((size_t)(d * 64 + b) << 8) + u] = c_reg[idx];
      hstate[((size_t)(d * 64 + b) << 8) + u] = h_reg[idx];
    }
}

// ===========================================================================
// SLOW FALLBACK PATH (round-2 passing version, used when ws is too small)
// ===========================================================================
template <typename TW, int XK, bool WRITE_SEQ>
__device__ __forceinline__ void lstm_body(const int* __restrict__ x, const TW* __restrict__ E,
                                          const __hip_bfloat16* __restrict__ seq_in,
                                          const TW* __restrict__ W, const TW* __restrict__ bias,
                                          const int len, const int b, const int dir,
                                          __hip_bfloat16* __restrict__ seq_out,
                                          float* __restrict__ hfin) {
  const int j = threadIdx.x;
  __shared__ float h[Hn];
  __shared__ float xb[XK];
  float hj = 0.0f, cj = 0.0f;
  h[j] = 0.0f;
  const float bfj = ldf(bias, j);
  const float bij = ldf(bias, Hn + j);
  const float bgj = ldf(bias, 2 * Hn + j);
  const float boj = ldf(bias, 3 * Hn + j);
  __syncthreads();
  for (int s = 0; s < Tn; ++s) {
    const int t = dir ? (Tn - 1 - s) : s;
    const bool active = (t < len);
    if (active) {
      if constexpr (XK == Dn) {
        const int tok = x[b * Tn + t];
        xb[j] = ldf(E, (long)tok * Dn + j);
      } else {
        const long base = ((long)(b * Tn + t)) * (2 * Hn);
        xb[j] = __bfloat162float(seq_in[base + j]);
        xb[j + Hn] = __bfloat162float(seq_in[base + j + Hn]);
      }
      __syncthreads();
      float af = bfj, ai = bij, ag = bgj, ao = boj;
#pragma unroll 4
      for (int k = 0; k < Hn; ++k) {
        const float hk = h[k];
        const long r = (long)k * (4 * Hn);
        af += hk * ldf(W, r + j);
        ai += hk * ldf(W, r + Hn + j);
        ag += hk * ldf(W, r + 2 * Hn + j);
        ao += hk * ldf(W, r + 3 * Hn + j);
      }
#pragma unroll 4
      for (int k = 0; k < XK; ++k) {
        const float xk = xb[k];
        const long r = (long)(Hn + k) * (4 * Hn);
        af += xk * ldf(W, r + j);
        ai += xk * ldf(W, r + Hn + j);
        ag += xk * ldf(W, r + 2 * Hn + j);
        ao += xk * ldf(W, r + 3 * Hn + j);
      }
      const float fg = 1.0f / (1.0f + expf(-af));
      const float ig = 1.0f / (1.0f + expf(-ai));
      const float gg = tanhf(ag);
      const float og = 1.0f / (1.0f + expf(-ao));
      const float cn = fg * cj + ig * gg;
      const float hn = og * tanhf(cn);
      __syncthreads();
      hj = hn;
      cj = cn;
      h[j] = hn;
      __syncthreads();
    }
    if constexpr (WRITE_SEQ) {
      seq_out[((long)(b * Tn + t)) * (2 * Hn) + dir * Hn + j] = __float2bfloat16(hj);
    }
  }
  if constexpr (!WRITE_SEQ) hfin[(dir * Bn + b) * Hn + j] = hj;
}

template <int XK, bool WRITE_SEQ>
__global__ void k_lstm(const int* __restrict__ x, const void* __restrict__ E,
                       const __hip_bfloat16* __restrict__ seq_in, const void* __restrict__ Wf,
                       const void* __restrict__ bf, const void* __restrict__ Wb,
                       const void* __restrict__ bb, const int* __restrict__ lengths,
                       const int* __restrict__ flag, __hip_bfloat16* __restrict__ seq_out,
                       float* __restrict__ hfin) {
  const int b = blockIdx.x & (Bn - 1);
  const int dir = blockIdx.x >> 6;
  const int len = lengths[b];
  const void* W = dir ? Wb : Wf;
  const void* bias = dir ? bb : bf;
  if (flag[0]) {
    lstm_body<float, XK, WRITE_SEQ>(x, (const float*)E, seq_in, (const float*)W,
                                    (const float*)bias, len, b, dir, seq_out, hfin);
  } else {
    lstm_body<__hip_bfloat16, XK, WRITE_SEQ>(x, (const __hip_bfloat16*)E, seq_in,
                                             (const __hip_bfloat16*)W, (const __hip_bfloat16*)bias,
                                             len, b, dir, seq_out, hfin);
  }
}

// ---------------------------------------------------------------------------
template <typename TW>
__device__ __forceinline__ void fc_body(const float* __restrict__ hfin, const TW* __restrict__ Wfc,
                                        const TW* __restrict__ bfc, TW* __restrict__ out) {
  const int idx = threadIdx.x;
  const int b = idx >> 1;
  const int cc = idx & 1;
  float acc = ldf(bfc, cc);
  for (int k = 0; k < Hn; ++k) acc += hfin[(0 * Bn + b) * Hn + k] * ldf(Wfc, k * 2 + cc);
  for (int k = 0; k < Hn; ++k) acc += hfin[(1 * Bn + b) * Hn + k] * ldf(Wfc, (Hn + k) * 2 + cc);
  if constexpr (sizeof(TW) == 2) {
    out[b * 2 + cc] = __float2bfloat16(acc);
  } else {
    out[b * 2 + cc] = acc;
  }
}

__global__ void k_fc(const float* __restrict__ hfin, const void* __restrict__ Wfc,
                     const void* __restrict__ bfc, const int* __restrict__ flag,
                     void* __restrict__ out) {
  if (flag[0]) {
    fc_body<float>(hfin, (const float*)Wfc, (const float*)bfc, (float*)out);
  } else {
    fc_body<__hip_bfloat16>(hfin, (const __hip_bfloat16*)Wfc, (const __hip_bfloat16*)bfc,
                            (__hip_bfloat16*)out);
  }
}

// ---------------------------------------------------------------------------
extern "C" void kernel_launch(void* const* d_in, const int* in_sizes, int n_in,
                              void* d_out, int out_size, void* d_ws, size_t ws_size,
                              hipStream_t stream) {
  const int* x = (const int*)d_in[0];
  const void* E = d_in[1];
  const void* Wf0 = d_in[2];
  const void* bf0 = d_in[3];
  const void* Wb0 = d_in[4];
  const void* bb0 = d_in[5];
  const void* Wf1 = d_in[6];
  const void* bf1 = d_in[7];
  const void* Wb1 = d_in[8];
  const void* bb1 = d_in[9];
  const void* Wfc = d_in[10];
  const void* bfc = d_in[11];

  char* ws = (char*)d_ws;
  int* flag = (int*)ws;                  // @0
  unsigned* ctr = (unsigned*)(ws + 64);  // 8 u32
  int* lengths = (int*)(ws + 256);

  const size_t MB = 1ull << 20;
  const size_t KB = 1024;

  k_detect<<<1, 256, 0, stream>>>((const unsigned short*)E, flag);
  k_lengths<<<Bn, 256, 0, stream>>>(x, lengths);

  // pick largest xproj chunk (Tc timesteps/dir, Tc*0.5 MB) that fits ws
  int Tc = 0;
  {
    const size_t fixed = 71 * MB + MB;  // weights/state/seq0 + slack
    const int cands[7] = {1024, 512, 256, 128, 64, 32, 16};
    for (int i = 0; i < 7; ++i)
      if (fixed + (size_t)cands[i] * 512 * KB <= ws_size) { Tc = cands[i]; break; }
  }

  if (Tc > 0) {
    float* biasbuf = (float*)(ws + 4096);                    // 16 KB
    __hip_bfloat16* whT = (__hip_bfloat16*)(ws + 1 * MB);    // [4][1024][256] = 2 MB
    __hip_bfloat16* wxT0 = (__hip_bfloat16*)(ws + 3 * MB);   // [2][1024][256] = 1 MB
    __hip_bfloat16* wxT1 = (__hip_bfloat16*)(ws + 4 * MB);   // [2][1024][512] = 2 MB
    __hip_bfloat16* hglob = (__hip_bfloat16*)(ws + 6 * MB);  // 128 KB
    float* cstate0 = (float*)(ws + 6 * MB + 128 * KB);       // 128 KB
    float* hstate0 = (float*)(ws + 6 * MB + 256 * KB);       // 128 KB
    float* cstate1 = (float*)(ws + 6 * MB + 384 * KB);       // 128 KB
    float* hstate1 = (float*)(ws + 6 * MB + 512 * KB);       // 128 KB
    __hip_bfloat16* seq0 = (__hip_bfloat16*)(ws + 7 * MB);   // [1024][64][512] = 64 MB
    float* xproj = (float*)(ws + 71 * MB);                   // [2][Tc][64][1024] f32

    k_prep_small<<<1, 256, 0, stream>>>(bf0, bb0, bf1, bb1, flag, biasbuf, ctr);
    k_prepw<<<dim3(12, 16, 4), 256, 0, stream>>>(Wf0, Wb0, Wf1, Wb1, flag, whT, wxT0, wxT1);

    const int P = Tn / Tc;
    // layer 0
    for (int p = 0; p < P; ++p) {
      const int s0 = p * Tc;
      const int t0f = s0, t0b = Tn - s0 - Tc;
      k_xproj<0><<<dim3(Tc, 16, 2), 256, 0, stream>>>(x, E, flag, nullptr, wxT0, biasbuf, xproj,
                                                      t0f, t0b, Tc);
      k_lstm_fast<true><<<8, 256, 0, stream>>>(whT, xproj, lengths, ctr, hglob, cstate0, hstate0,
                                               seq0, s0, Tc);
    }
    // layer 1
    for (int p = 0; p < P; ++p) {
      const int s0 = p * Tc;
      const int t0f = s0, t0b = Tn - s0 - Tc;
      k_xproj<1><<<dim3(Tc, 16, 2), 256, 0, stream>>>(x, E, flag, seq0, wxT1, biasbuf + 2048,
                                                      xproj, t0f, t0b, Tc);
      k_lstm_fast<false><<<8, 256, 0, stream>>>(whT + 2 * 1024 * 256, xproj, lengths, ctr + 2,
                                                hglob, cstate1, hstate1, nullptr, s0, Tc);
    }
    k_fc<<<1, 128, 0, stream>>>(hstate1, Wfc, bfc, flag, d_out);
  } else {
    // slow fallback (round-2 passing path)
    __hip_bfloat16* seq0 = (__hip_bfloat16*)(ws + 4096);
    const size_t seq0_bytes = (size_t)Bn * Tn * 2 * Hn * sizeof(__hip_bfloat16);
    float* hfin = (float*)(ws + 4096 + seq0_bytes);
    k_lstm<Dn, true><<<2 * Bn, 256, 0, stream>>>(x, E, nullptr, Wf0, bf0, Wb0, bb0, lengths, flag,
                                                 seq0, nullptr);
    k_lstm<2 * Hn, false><<<2 * Bn, 256, 0, stream>>>(x, E, seq0, Wf1, bf1, Wb1, bb1, lengths,
                                                      flag, nullptr, hfin);
    k_fc<<<1, 128, 0, stream>>>(hfin, Wfc, bfc, flag, d_out);
  }
}